// Round 1
// baseline (189.242 us; speedup 1.0000x reference)
//
#include <hip/hip_runtime.h>

// Problem constants (from setup_inputs)
#define H_  1024
#define W_  1024
#define B_  4
#define GH  16
#define GW  16
#define GD  8
#define NC  12

// Tiling: block (64,4) = 256 threads. Tile = 64 wide x 16 tall.
// Each thread computes a vertical strip of 4 pixels (amortizes conv halo).
#define TW 64
#define TH 16
#define LROWS (TH + 2)        // 18 LDS image rows (+1 halo top/bottom)
#define LROWF ((TW + 2) * 3)  // 198 floats per LDS row (66 px * 3ch)

__global__ __launch_bounds__(256)
void fused_conv_slice(const float* __restrict__ grid,
                      const float* __restrict__ guide,
                      const float* __restrict__ image,
                      const float* __restrict__ conv_w,
                      const float* __restrict__ conv_b,
                      float* __restrict__ out) {
    __shared__ float s_img[LROWS * LROWF];  // 14256 B

    const int tx  = threadIdx.x;   // 0..63
    const int tyq = threadIdx.y;   // 0..3
    const int bx  = blockIdx.x;    // 0..15
    const int by  = blockIdx.y;    // 0..63
    const int b   = blockIdx.z;    // 0..3

    const int x0 = bx * TW;
    const int y0 = by * TH;

    // ---- stage image tile (+halo) into LDS, zero-padded at borders ----
    const int tid = tyq * 64 + tx;
    const int imgbase = b * (H_ * W_ * 3);
    #pragma unroll
    for (int it = 0; it < 14; ++it) {
        int f = tid + it * 256;
        if (f < LROWS * LROWF) {
            int r   = f / LROWF;
            int rem = f - r * LROWF;
            int c3  = rem / 3;
            int ch  = rem - c3 * 3;
            int yy  = y0 - 1 + r;
            int xx  = x0 - 1 + c3;
            float v = 0.0f;
            if (yy >= 0 && yy < H_ && xx >= 0 && xx < W_)
                v = image[imgbase + (yy * W_ + xx) * 3 + ch];
            s_img[f] = v;
        }
    }

    // ---- conv weights: uniform reads -> expect SGPRs ----
    float wgt[81];
    #pragma unroll
    for (int i = 0; i < 81; ++i) wgt[i] = conv_w[i];
    float bias0 = conv_b[0], bias1 = conv_b[1], bias2 = conv_b[2];

    __syncthreads();

    const int x = x0 + tx;
    const float* gB = grid + b * (GH * GW * GD * NC);
    const int guidebase = b * (H_ * W_);
    const int outbase   = b * (H_ * W_ * 3);

    float r0[9], r1[9], r2[9];
    const int lr = tyq * 4;  // LDS row offset: pixel j uses LDS rows lr+j .. lr+j+2

    // load a 9-float horizontal window (cols tx-1..tx+1, 3 ch) from LDS row r
    auto loadrow = [&](int r, float* dst) {
        const float* p = &s_img[r * LROWF + tx * 3];
        #pragma unroll
        for (int i = 0; i < 9; ++i) dst[i] = p[i];
    };

    // 3x3x3->3 conv at this pixel given its three input rows
    auto conv3 = [&](const float* ra, const float* rb, const float* rc, float* acc) {
        acc[0] = bias0; acc[1] = bias1; acc[2] = bias2;
        const float* rows[3] = {ra, rb, rc};
        #pragma unroll
        for (int kh = 0; kh < 3; ++kh)
            #pragma unroll
            for (int kw = 0; kw < 3; ++kw)
                #pragma unroll
                for (int ci = 0; ci < 3; ++ci) {
                    float v = rows[kh][kw * 3 + ci];
                    int wb = ((kh * 3 + kw) * 3 + ci) * 3;
                    acc[0] += v * wgt[wb + 0];
                    acc[1] += v * wgt[wb + 1];
                    acc[2] += v * wgt[wb + 2];
                }
    };

    // bilateral slice + affine apply for pixel (x,y), conv output a[3]
    auto slice_apply = [&](int y, const float* a) {
        float gv  = guide[guidebase + y * W_ + x];
        float gxf = (x + 0.5f) * (1.0f / 64.0f) - 0.5f;
        float gyf = (y + 0.5f) * (1.0f / 64.0f) - 0.5f;
        float gzf = gv * 8.0f - 0.5f;
        float fx = floorf(gxf), fy = floorf(gyf), fz = floorf(gzf);
        float tfx = gxf - fx, tfy = gyf - fy, tfz = gzf - fz;
        int xs[2], ys[2], zs[2];
        xs[0] = min(max((int)fx, 0), GW - 1);  xs[1] = min(max((int)fx + 1, 0), GW - 1);
        ys[0] = min(max((int)fy, 0), GH - 1);  ys[1] = min(max((int)fy + 1, 0), GH - 1);
        zs[0] = min(max((int)fz, 0), GD - 1);  zs[1] = min(max((int)fz + 1, 0), GD - 1);
        float wx[2] = {1.0f - tfx, tfx};
        float wy[2] = {1.0f - tfy, tfy};
        float wz[2] = {1.0f - tfz, tfz};

        float c[12];
        #pragma unroll
        for (int i = 0; i < 12; ++i) c[i] = 0.0f;

        #pragma unroll
        for (int dz = 0; dz < 2; ++dz)
            #pragma unroll
            for (int dy = 0; dy < 2; ++dy)
                #pragma unroll
                for (int dx = 0; dx < 2; ++dx) {
                    float w = wz[dz] * wy[dy] * wx[dx];
                    const float4* gp = (const float4*)(gB +
                        (((ys[dy] * GW + xs[dx]) * GD + zs[dz]) * NC));
                    float4 g0 = gp[0], g1 = gp[1], g2 = gp[2];
                    c[0]  += w * g0.x; c[1]  += w * g0.y; c[2]  += w * g0.z; c[3]  += w * g0.w;
                    c[4]  += w * g1.x; c[5]  += w * g1.y; c[6]  += w * g1.z; c[7]  += w * g1.w;
                    c[8]  += w * g2.x; c[9]  += w * g2.y; c[10] += w * g2.z; c[11] += w * g2.w;
                }

        int oidx = outbase + (y * W_ + x) * 3;
        out[oidx + 0] = c[0] * a[0] + c[1] * a[1] + c[2]  * a[2] + c[3];
        out[oidx + 1] = c[4] * a[0] + c[5] * a[1] + c[6]  * a[2] + c[7];
        out[oidx + 2] = c[8] * a[0] + c[9] * a[1] + c[10] * a[2] + c[11];
    };

    float acc[3];

    // j=0: rows lr+0..lr+2
    loadrow(lr + 0, r0);
    loadrow(lr + 1, r1);
    loadrow(lr + 2, r2);
    conv3(r0, r1, r2, acc);
    slice_apply(y0 + lr + 0, acc);

    // j=1: rows lr+1..lr+3 (rotate: r0 <- new row)
    loadrow(lr + 3, r0);
    conv3(r1, r2, r0, acc);
    slice_apply(y0 + lr + 1, acc);

    // j=2: rows lr+2..lr+4
    loadrow(lr + 4, r1);
    conv3(r2, r0, r1, acc);
    slice_apply(y0 + lr + 2, acc);

    // j=3: rows lr+3..lr+5
    loadrow(lr + 5, r2);
    conv3(r0, r1, r2, acc);
    slice_apply(y0 + lr + 3, acc);
}

extern "C" void kernel_launch(void* const* d_in, const int* in_sizes, int n_in,
                              void* d_out, int out_size, void* d_ws, size_t ws_size,
                              hipStream_t stream) {
    const float* grid   = (const float*)d_in[0];
    const float* guide  = (const float*)d_in[1];
    const float* image  = (const float*)d_in[2];
    const float* conv_w = (const float*)d_in[3];
    const float* conv_b = (const float*)d_in[4];
    float* out = (float*)d_out;

    dim3 block(64, 4, 1);
    dim3 grid_dim(W_ / TW, H_ / TH, B_);  // (16, 64, 4)
    fused_conv_slice<<<grid_dim, block, 0, stream>>>(grid, guide, image, conv_w, conv_b, out);
}

// Round 2
// 174.898 us; speedup vs baseline: 1.0820x; 1.0820x over previous
//
#include <hip/hip_runtime.h>

// Problem constants
#define H_  1024
#define W_  1024
#define B_  4
#define GH  16
#define GW  16
#define GD  8
#define NC  12
#define CELLF (GD * NC)      // 96 floats per (y,x) grid cell
#define YROWF (GW * CELLF)   // 1536 floats per grid y-row

// Tiling: block (64,4) = 256 threads; tile 64 wide x 16 tall; 4 rows/thread.
#define TW 64
#define TH 16
#define LROWS (TH + 2)        // 18 LDS image rows
#define LROWF ((TW + 2) * 3)  // 198 floats per LDS image row
#define TABF (3 * CELLF)      // 288 floats per wave's y-interp table

__device__ __forceinline__ float4 wsum4(float m0, const float4 a,
                                        float m1, const float4 b,
                                        float m2, const float4 c,
                                        float m3, const float4 d) {
    float4 r;
    r.x = m0 * a.x + m1 * b.x + m2 * c.x + m3 * d.x;
    r.y = m0 * a.y + m1 * b.y + m2 * c.y + m3 * d.y;
    r.z = m0 * a.z + m1 * b.z + m2 * c.z + m3 * d.z;
    r.w = m0 * a.w + m1 * b.w + m2 * c.w + m3 * d.w;
    return r;
}

__global__ __launch_bounds__(256)
void fused_conv_slice(const float* __restrict__ grid,
                      const float* __restrict__ guide,
                      const float* __restrict__ image,
                      const float* __restrict__ conv_w,
                      const float* __restrict__ conv_b,
                      float* __restrict__ out)
{
    __shared__ float s_img[LROWS * LROWF];  // 14256 B
    __shared__ float s_tab[4][TABF];        //  4608 B (per-wave private tables)

    const int tx  = threadIdx.x;   // 0..63 (one wave per tyq)
    const int tyq = threadIdx.y;   // 0..3
    const int bx  = blockIdx.x;
    const int by  = blockIdx.y;
    const int b   = blockIdx.z;
    const int x0 = bx * TW;
    const int y0 = by * TH;
    const int tid = tyq * 64 + tx;
    const int imgbase = b * (H_ * W_ * 3);

    // ---- stage image tile (+1 halo) into LDS ----
    #pragma unroll
    for (int it = 0; it < 14; ++it) {
        int f = tid + it * 256;
        if (f < LROWS * LROWF) {
            int r   = f / LROWF;
            int rem = f - r * LROWF;
            int c3  = rem / 3;
            int ch  = rem - c3 * 3;
            int yy  = y0 - 1 + r;
            int xx  = x0 - 1 + c3;
            float v = 0.0f;
            if (yy >= 0 && yy < H_ && xx >= 0 && xx < W_)
                v = image[imgbase + (yy * W_ + xx) * 3 + ch];
            s_img[f] = v;
        }
    }

    // conv weights: uniform loads -> SGPR/s_load path
    float wgt[81];
    #pragma unroll
    for (int i = 0; i < 81; ++i) wgt[i] = conv_w[i];
    float bias0 = conv_b[0], bias1 = conv_b[1], bias2 = conv_b[2];

    __syncthreads();

    // ---- conv for this thread's 4 rows, results kept in registers ----
    const int lr = tyq * 4;
    float r0[9], r1[9], r2[9];
    float acc4[4][3];

    auto loadrow = [&](int r, float* dst) {
        const float* p = &s_img[r * LROWF + tx * 3];
        #pragma unroll
        for (int i = 0; i < 9; ++i) dst[i] = p[i];
    };
    auto conv3 = [&](const float* ra, const float* rb, const float* rc, float* acc) {
        acc[0] = bias0; acc[1] = bias1; acc[2] = bias2;
        const float* rows[3] = {ra, rb, rc};
        #pragma unroll
        for (int kh = 0; kh < 3; ++kh)
            #pragma unroll
            for (int kw = 0; kw < 3; ++kw)
                #pragma unroll
                for (int ci = 0; ci < 3; ++ci) {
                    float v = rows[kh][kw * 3 + ci];
                    int wb = ((kh * 3 + kw) * 3 + ci) * 3;
                    acc[0] += v * wgt[wb + 0];
                    acc[1] += v * wgt[wb + 1];
                    acc[2] += v * wgt[wb + 2];
                }
    };

    loadrow(lr + 0, r0); loadrow(lr + 1, r1); loadrow(lr + 2, r2);
    conv3(r0, r1, r2, acc4[0]);
    loadrow(lr + 3, r0); conv3(r1, r2, r0, acc4[1]);
    loadrow(lr + 4, r1); conv3(r2, r0, r1, acc4[2]);
    loadrow(lr + 5, r2); conv3(r0, r1, r2, acc4[3]);

    // ---- guide prefetch (4 independent coalesced loads) ----
    const int x = x0 + tx;
    const int guidebase = b * (H_ * W_);
    float g4[4];
    #pragma unroll
    for (int j = 0; j < 4; ++j)
        g4[j] = guide[guidebase + (y0 + lr + j) * W_ + x];

    // ---- per-thread x-interp setup (constant across the 4 rows) ----
    float gxf = (x + 0.5f) * (1.0f / 64.0f) - 0.5f;
    float fxf = floorf(gxf);
    float txw = gxf - fxf;
    float wxa = 1.0f - txw, wxb = txw;
    int s0 = (int)fxf - (bx - 1);  // table slot of left x-corner: 0 (tx<32) or 1

    // block-uniform cell set {bx-1, bx, bx+1} clamped (clamped-index semantics:
    // weights stay (1-t, t), duplicate cells sum to the reference's clip behavior)
    int cells[3];
    cells[0] = max(bx - 1, 0);
    cells[1] = bx;
    cells[2] = min(bx + 1, GW - 1);

    const float* gB = grid + b * (GH * GW * GD * NC);
    float* Tw = &s_tab[tyq][0];
    const int outbase = b * (H_ * W_ * 3);

    #pragma unroll
    for (int j = 0; j < 4; ++j) {
        int y = y0 + lr + j;

        // ---- wave-uniform y-lerp parameters ----
        float gyf = (y + 0.5f) * (1.0f / 64.0f) - 0.5f;
        float fyf = floorf(gyf);
        float tyw = gyf - fyf;
        int iy = (int)fyf;
        int yi0 = min(max(iy, 0), GH - 1);
        int yi1 = min(max(iy + 1, 0), GH - 1);
        float wy0 = 1.0f - tyw, wy1 = tyw;
        const float* G0 = gB + yi0 * YROWF;
        const float* G1 = gB + yi1 * YROWF;

        // ---- cooperative fill of T[3][8][12] = 144 float2 elements ----
        #pragma unroll
        for (int k = 0; k < 3; ++k) {
            int ee = tx + k * 64;
            if (k < 2 || tx < 16) {
                int s = ee / 48;            // 48 float2 per cell slot
                int r = ee - s * 48;
                const float2* q0 = (const float2*)(G0 + cells[s] * CELLF);
                const float2* q1 = (const float2*)(G1 + cells[s] * CELLF);
                float2 v0 = q0[r], v1 = q1[r];
                float2 w;
                w.x = wy0 * v0.x + wy1 * v1.x;
                w.y = wy0 * v0.y + wy1 * v1.y;
                ((float2*)Tw)[ee] = w;
            }
        }
        __syncthreads();  // RAW fence for the table (uniform across block)

        // ---- slice: z-pair + x-lerp from the table ----
        float gzf = g4[j] * 8.0f - 0.5f;
        float fzf = floorf(gzf);
        float tz = gzf - fzf;
        int iz = (int)fzf;                       // -1..7
        int zb = min(max(iz, 0), GD - 2);        // contiguous z-pair base
        float wA = (iz < 0) ? 1.0f : ((iz > GD - 2) ? 0.0f : (1.0f - tz));
        float wB = 1.0f - wA;

        const float4* pA = (const float4*)(Tw + (s0 * GD + zb) * NC);  // 16B aligned
        const float4* pB = pA + 24;  // next cell slot (+96 floats)
        float m0 = wxa * wA, m1 = wxa * wB, m2 = wxb * wA, m3 = wxb * wB;

        float4 c0 = wsum4(m0, pA[0], m1, pA[3], m2, pB[0], m3, pB[3]);
        float4 c1 = wsum4(m0, pA[1], m1, pA[4], m2, pB[1], m3, pB[4]);
        float4 c2 = wsum4(m0, pA[2], m1, pA[5], m2, pB[2], m3, pB[5]);

        float a0 = acc4[j][0], a1 = acc4[j][1], a2 = acc4[j][2];
        int oidx = outbase + (y * W_ + x) * 3;
        out[oidx + 0] = c0.x * a0 + c0.y * a1 + c0.z * a2 + c0.w;
        out[oidx + 1] = c1.x * a0 + c1.y * a1 + c1.z * a2 + c1.w;
        out[oidx + 2] = c2.x * a0 + c2.y * a1 + c2.z * a2 + c2.w;
        // WAR on the table across rows is safe: per-wave private region +
        // in-order DS execution within a wave; next RAW gets the barrier above.
    }
}

extern "C" void kernel_launch(void* const* d_in, const int* in_sizes, int n_in,
                              void* d_out, int out_size, void* d_ws, size_t ws_size,
                              hipStream_t stream) {
    const float* grid   = (const float*)d_in[0];
    const float* guide  = (const float*)d_in[1];
    const float* image  = (const float*)d_in[2];
    const float* conv_w = (const float*)d_in[3];
    const float* conv_b = (const float*)d_in[4];
    float* out = (float*)d_out;

    dim3 block(64, 4, 1);
    dim3 grid_dim(W_ / TW, H_ / TH, B_);  // (16, 64, 4)
    fused_conv_slice<<<grid_dim, block, 0, stream>>>(grid, guide, image, conv_w, conv_b, out);
}

// Round 3
// 143.243 us; speedup vs baseline: 1.3211x; 1.2210x over previous
//
#include <hip/hip_runtime.h>

// Problem constants
#define H_  1024
#define W_  1024
#define B_  4
#define GH  16
#define GW  16
#define GD  8
#define NC  12
#define CELLF (GD * NC)      // 96 floats per (y,x) grid cell
#define YROWF (GW * CELLF)   // 1536 floats per grid y-row

// Tiling: block (64,4) = 256 threads; tile 64 wide x 16 tall; 4 rows/thread.
#define TW 64
#define TH 16
#define LROWS (TH + 2)       // 18 image rows in LDS (+1 halo each side)
#define LCOLS (TW + 2)       // 66 px per LDS row
#define TABF (3 * CELLF)     // 288 floats per row-table (3 x-cells x 8z x 12)

__device__ __forceinline__ float4 wsum4(float m0, const float4 a,
                                        float m1, const float4 b,
                                        float m2, const float4 c,
                                        float m3, const float4 d) {
    float4 r;
    r.x = m0 * a.x + m1 * b.x + m2 * c.x + m3 * d.x;
    r.y = m0 * a.y + m1 * b.y + m2 * c.y + m3 * d.y;
    r.z = m0 * a.z + m1 * b.z + m2 * c.z + m3 * d.z;
    r.w = m0 * a.w + m1 * b.w + m2 * c.w + m3 * d.w;
    return r;
}

__global__ __launch_bounds__(256)
void fused_conv_slice(const float* __restrict__ grid,
                      const float* __restrict__ guide,
                      const float* __restrict__ image,
                      const float* __restrict__ conv_w,
                      const float* __restrict__ conv_b,
                      float* __restrict__ out)
{
    // image tile as float4 pixels (w unused) -> ds_read_b128 conv reads,
    // conflict-free (16 lanes x 16B = all 32 banks exactly once per phase)
    __shared__ float4 s_img4[LROWS][LCOLS];           // 19008 B
    __shared__ __align__(16) float s_tab[TH][TABF];   // 18432 B  (~37.4 KB total)

    const int tx  = threadIdx.x;   // 0..63 (one wave per tyq)
    const int tyq = threadIdx.y;   // 0..3
    const int bx  = blockIdx.x;
    const int by  = blockIdx.y;
    const int b   = blockIdx.z;
    const int x0 = bx * TW;
    const int y0 = by * TH;
    const int tid = tyq * 64 + tx;
    const int imgbase = b * (H_ * W_ * 3);

    // ---- stage image tile (+1 halo), no div/mod addressing ----
    auto stage_px = [&](int rr, int c) {
        int yy = y0 - 1 + rr;
        int xx = x0 - 1 + c;
        float4 v = make_float4(0.f, 0.f, 0.f, 0.f);
        if (yy >= 0 && yy < H_ && xx >= 0 && xx < W_) {
            const float* p = image + imgbase + (yy * W_ + xx) * 3;
            v.x = p[0]; v.y = p[1]; v.z = p[2];
        }
        s_img4[rr][c] = v;
    };
    #pragma unroll
    for (int rr0 = 0; rr0 < LROWS; rr0 += 4) {
        int rr = rr0 + tyq;
        if (rr < LROWS) {
            stage_px(rr, tx);
            if (tx < 2) stage_px(rr, TW + tx);
        }
    }

    // ---- upfront cooperative fill of ALL 16 row-tables (one barrier total) ----
    // thread handles table row rr = tid>>4 (each wave fills exactly its own 4 rows)
    int cells[3];
    cells[0] = max(bx - 1, 0);
    cells[1] = bx;
    cells[2] = min(bx + 1, GW - 1);
    const float* gB = grid + b * (GH * GW * GD * NC);
    {
        int rr = tid >> 4;
        int le = tid & 15;
        int y  = y0 + rr;
        float gyf = (y + 0.5f) * (1.0f / 64.0f) - 0.5f;
        float fyf = floorf(gyf);
        float tyw = gyf - fyf;
        int iy = (int)fyf;
        int yi0 = min(max(iy, 0), GH - 1);
        int yi1 = min(max(iy + 1, 0), GH - 1);
        float wy0 = 1.0f - tyw, wy1 = tyw;
        const float2* G0 = (const float2*)(gB + yi0 * YROWF);
        const float2* G1 = (const float2*)(gB + yi1 * YROWF);
        float2* T = (float2*)&s_tab[rr][0];
        #pragma unroll
        for (int k = 0; k < 9; ++k) {
            int e = le + k * 16;                       // 0..143 (144 float2 per table)
            int s = (e >= 96) ? 2 : ((e >= 48) ? 1 : 0);  // cell slot (16-aligned groups)
            int re = e - s * 48;
            int off = cells[s] * 48 + re;
            float2 v0 = G0[off], v1 = G1[off];
            float2 w;
            w.x = wy0 * v0.x + wy1 * v1.x;
            w.y = wy0 * v0.y + wy1 * v1.y;
            T[e] = w;
        }
    }

    // ---- guide prefetch (latency hides under staging/fill) ----
    const int x = x0 + tx;
    const int lr = tyq * 4;
    const int guidebase = b * (H_ * W_);
    float g4[4];
    #pragma unroll
    for (int j = 0; j < 4; ++j)
        g4[j] = guide[guidebase + (y0 + lr + j) * W_ + x];

    // ---- conv weights: uniform reads -> SGPRs ----
    float wgt[81];
    #pragma unroll
    for (int i = 0; i < 81; ++i) wgt[i] = conv_w[i];
    float bias0 = conv_b[0], bias1 = conv_b[1], bias2 = conv_b[2];

    __syncthreads();  // the ONLY barrier

    // ---- conv for this thread's 4 rows (float4 LDS reads) ----
    float4 r0[3], r1[3], r2[3];
    float acc4[4][3];

    auto loadrow = [&](int r, float4* d) {
        d[0] = s_img4[r][tx];
        d[1] = s_img4[r][tx + 1];
        d[2] = s_img4[r][tx + 2];
    };
    auto conv3 = [&](const float4* ra, const float4* rb, const float4* rc, float* acc) {
        acc[0] = bias0; acc[1] = bias1; acc[2] = bias2;
        const float4* rows[3] = {ra, rb, rc};
        #pragma unroll
        for (int kh = 0; kh < 3; ++kh)
            #pragma unroll
            for (int kw = 0; kw < 3; ++kw) {
                float4 v4 = rows[kh][kw];
                float v[3] = {v4.x, v4.y, v4.z};
                #pragma unroll
                for (int ci = 0; ci < 3; ++ci) {
                    int wb = ((kh * 3 + kw) * 3 + ci) * 3;
                    acc[0] += v[ci] * wgt[wb + 0];
                    acc[1] += v[ci] * wgt[wb + 1];
                    acc[2] += v[ci] * wgt[wb + 2];
                }
            }
    };

    loadrow(lr + 0, r0); loadrow(lr + 1, r1); loadrow(lr + 2, r2);
    conv3(r0, r1, r2, acc4[0]);
    loadrow(lr + 3, r0); conv3(r1, r2, r0, acc4[1]);
    loadrow(lr + 4, r1); conv3(r2, r0, r1, acc4[2]);
    loadrow(lr + 5, r2); conv3(r0, r1, r2, acc4[3]);

    // ---- per-thread x-interp setup (constant across the 4 rows) ----
    float gxf = (x + 0.5f) * (1.0f / 64.0f) - 0.5f;
    float fxf = floorf(gxf);
    float txw = gxf - fxf;
    float wxa = 1.0f - txw, wxb = txw;
    int s0 = (int)fxf - (bx - 1);   // table slot of left x-corner: 0 or 1

    const int outbase = b * (H_ * W_ * 3);

    #pragma unroll
    for (int j = 0; j < 4; ++j) {
        int y = y0 + lr + j;
        const float* Tw = &s_tab[lr + j][0];

        // z-pair + x-lerp from this row's table (barrier-free)
        float gzf = g4[j] * 8.0f - 0.5f;
        float fzf = floorf(gzf);
        float tz = gzf - fzf;
        int iz = (int)fzf;                    // -1..7
        int zb = min(max(iz, 0), GD - 2);     // contiguous z-pair base
        float wA = (iz < 0) ? 1.0f : ((iz > GD - 2) ? 0.0f : (1.0f - tz));
        float wB = 1.0f - wA;

        const float4* pA = (const float4*)(Tw + (s0 * GD + zb) * NC);  // 16B aligned
        const float4* pB = pA + 24;  // next x-cell slot (+96 floats)
        float m0 = wxa * wA, m1 = wxa * wB, m2 = wxb * wA, m3 = wxb * wB;

        float4 c0 = wsum4(m0, pA[0], m1, pA[3], m2, pB[0], m3, pB[3]);
        float4 c1 = wsum4(m0, pA[1], m1, pA[4], m2, pB[1], m3, pB[4]);
        float4 c2 = wsum4(m0, pA[2], m1, pA[5], m2, pB[2], m3, pB[5]);

        float a0 = acc4[j][0], a1 = acc4[j][1], a2 = acc4[j][2];
        int oidx = outbase + (y * W_ + x) * 3;
        out[oidx + 0] = c0.x * a0 + c0.y * a1 + c0.z * a2 + c0.w;
        out[oidx + 1] = c1.x * a0 + c1.y * a1 + c1.z * a2 + c1.w;
        out[oidx + 2] = c2.x * a0 + c2.y * a1 + c2.z * a2 + c2.w;
    }
}

extern "C" void kernel_launch(void* const* d_in, const int* in_sizes, int n_in,
                              void* d_out, int out_size, void* d_ws, size_t ws_size,
                              hipStream_t stream) {
    const float* grid   = (const float*)d_in[0];
    const float* guide  = (const float*)d_in[1];
    const float* image  = (const float*)d_in[2];
    const float* conv_w = (const float*)d_in[3];
    const float* conv_b = (const float*)d_in[4];
    float* out = (float*)d_out;

    dim3 block(64, 4, 1);
    dim3 grid_dim(W_ / TW, H_ / TH, B_);  // (16, 64, 4)
    fused_conv_slice<<<grid_dim, block, 0, stream>>>(grid, guide, image, conv_w, conv_b, out);
}

// Round 4
// 137.008 us; speedup vs baseline: 1.3812x; 1.0455x over previous
//
#include <hip/hip_runtime.h>

// Problem constants
#define H_  1024
#define W_  1024
#define B_  4
#define GH  16
#define GW  16
#define GD  8
#define NC  12
#define CELLF (GD * NC)      // 96 floats per (y,x) grid cell
#define YROWF (GW * CELLF)   // 1536 floats per grid y-row

// Tiling: block (64,4) = 256 threads; tile 64 wide x 8 tall; 2 rows/thread.
// TH=8 keeps LDS under 20 KB -> 8 blocks/CU (32 waves = full wave capacity).
#define TW 64
#define TH 8
#define LROWS (TH + 2)       // 10 image rows in LDS (+1 halo each side)
#define LCOLS (TW + 2)       // 66 px per LDS row
#define TABF (3 * CELLF)     // 288 floats per row-table (3 x-cells x 8z x 12)

typedef float f2 __attribute__((ext_vector_type(2)));

__global__ __launch_bounds__(256)
void fused_conv_slice(const float* __restrict__ grid,
                      const float* __restrict__ guide,
                      const float* __restrict__ image,
                      const float* __restrict__ conv_w,
                      const float* __restrict__ conv_b,
                      float* __restrict__ out)
{
    __shared__ float4 s_img4[LROWS][LCOLS];           // 10560 B
    __shared__ __align__(16) float s_tab[TH][TABF];   //  9216 B  (~19.8 KB total)

    const int tx  = threadIdx.x;   // 0..63 (one wave per tyq)
    const int tyq = threadIdx.y;   // 0..3
    const int bx  = blockIdx.x;
    const int by  = blockIdx.y;
    const int b   = blockIdx.z;
    const int x0 = bx * TW;
    const int y0 = by * TH;
    const int tid = tyq * 64 + tx;
    const int imgbase = b * (H_ * W_ * 3);

    // ---- stage image tile (+1 halo) ----
    auto stage_px = [&](int rr, int c) {
        int yy = y0 - 1 + rr;
        int xx = x0 - 1 + c;
        float4 v = make_float4(0.f, 0.f, 0.f, 0.f);
        if (yy >= 0 && yy < H_ && xx >= 0 && xx < W_) {
            const float* p = image + imgbase + (yy * W_ + xx) * 3;
            v.x = p[0]; v.y = p[1]; v.z = p[2];
        }
        s_img4[rr][c] = v;
    };
    #pragma unroll
    for (int rr0 = 0; rr0 < LROWS; rr0 += 4) {
        int rr = rr0 + tyq;
        if (rr < LROWS) {
            stage_px(rr, tx);
            if (tx < 2) stage_px(rr, TW + tx);
        }
    }

    // ---- cooperative fill of the 8 row-tables (one barrier total) ----
    int cells[3];
    cells[0] = max(bx - 1, 0);
    cells[1] = bx;
    cells[2] = min(bx + 1, GW - 1);
    const float* gB = grid + b * (GH * GW * GD * NC);
    {
        int rr = tid >> 5;          // table row 0..7 (32 threads each)
        int le = tid & 31;
        int y  = y0 + rr;
        float gyf = (y + 0.5f) * (1.0f / 64.0f) - 0.5f;
        float fyf = floorf(gyf);
        float tyw = gyf - fyf;
        int iy = (int)fyf;
        int yi0 = min(max(iy, 0), GH - 1);
        int yi1 = min(max(iy + 1, 0), GH - 1);
        float wy0 = 1.0f - tyw, wy1 = tyw;
        const float2* G0 = (const float2*)(gB + yi0 * YROWF);
        const float2* G1 = (const float2*)(gB + yi1 * YROWF);
        float2* T = (float2*)&s_tab[rr][0];
        #pragma unroll
        for (int k = 0; k < 5; ++k) {
            int e = le + k * 32;                          // 0..159; table has 144 float2
            if (e < 144) {
                int s = (e >= 96) ? 2 : ((e >= 48) ? 1 : 0);  // 16-aligned groups
                int re = e - s * 48;
                int off = cells[s] * 48 + re;
                float2 v0 = G0[off], v1 = G1[off];
                float2 w;
                w.x = wy0 * v0.x + wy1 * v1.x;
                w.y = wy0 * v0.y + wy1 * v1.y;
                T[e] = w;
            }
        }
    }

    // ---- guide prefetch ----
    const int x = x0 + tx;
    const int lr = tyq * 2;
    const int guidebase = b * (H_ * W_);
    float g2[2];
    #pragma unroll
    for (int j = 0; j < 2; ++j)
        g2[j] = guide[guidebase + (y0 + lr + j) * W_ + x];

    // ---- conv weights: uniform reads -> SGPRs (kept scalar on purpose:
    //      packed ops would force weights into VGPRs and break the 8-wave cap)
    float wgt[81];
    #pragma unroll
    for (int i = 0; i < 81; ++i) wgt[i] = conv_w[i];
    float bias0 = conv_b[0], bias1 = conv_b[1], bias2 = conv_b[2];

    __syncthreads();  // the ONLY barrier

    // ---- conv for this thread's 2 rows ----
    float4 r0[3], r1[3], r2[3];
    float acc2r[2][3];

    auto loadrow = [&](int r, float4* d) {
        d[0] = s_img4[r][tx];
        d[1] = s_img4[r][tx + 1];
        d[2] = s_img4[r][tx + 2];
    };
    auto conv3 = [&](const float4* ra, const float4* rb, const float4* rc, float* acc) {
        acc[0] = bias0; acc[1] = bias1; acc[2] = bias2;
        const float4* rows[3] = {ra, rb, rc};
        #pragma unroll
        for (int kh = 0; kh < 3; ++kh)
            #pragma unroll
            for (int kw = 0; kw < 3; ++kw) {
                float4 v4 = rows[kh][kw];
                float v[3] = {v4.x, v4.y, v4.z};
                #pragma unroll
                for (int ci = 0; ci < 3; ++ci) {
                    int wb = ((kh * 3 + kw) * 3 + ci) * 3;
                    acc[0] += v[ci] * wgt[wb + 0];
                    acc[1] += v[ci] * wgt[wb + 1];
                    acc[2] += v[ci] * wgt[wb + 2];
                }
            }
    };

    loadrow(lr + 0, r0); loadrow(lr + 1, r1); loadrow(lr + 2, r2);
    conv3(r0, r1, r2, acc2r[0]);
    loadrow(lr + 3, r0);
    conv3(r1, r2, r0, acc2r[1]);

    // ---- per-thread x-interp setup ----
    float gxf = (x + 0.5f) * (1.0f / 64.0f) - 0.5f;
    float fxf = floorf(gxf);
    float txw = gxf - fxf;
    float wxa = 1.0f - txw, wxb = txw;
    int s0 = (int)fxf - (bx - 1);   // table x-slot of left corner: 0 or 1

    const int outbase = b * (H_ * W_ * 3);

    #pragma unroll
    for (int j = 0; j < 2; ++j) {
        int y = y0 + lr + j;
        const float* Tw = &s_tab[lr + j][0];

        float gzf = g2[j] * 8.0f - 0.5f;
        float fzf = floorf(gzf);
        float tz = gzf - fzf;
        int iz = (int)fzf;                    // -1..7
        int zb = min(max(iz, 0), GD - 2);     // contiguous z-pair base
        float wA = (iz < 0) ? 1.0f : ((iz > GD - 2) ? 0.0f : (1.0f - tz));
        float wB = 1.0f - wA;

        const float4* pA = (const float4*)(Tw + (s0 * GD + zb) * NC);  // 16B aligned
        const float4* pB = pA + 24;  // next x-cell (+96 floats)
        float m0 = wxa * wA, m1 = wxa * wB, m2 = wxb * wA, m3 = wxb * wB;
        f2 m0v = {m0, m0}, m1v = {m1, m1}, m2v = {m2, m2}, m3v = {m3, m3};

        float4 A0 = pA[0], A1 = pA[1], A2 = pA[2];   // corner (s0, zb)
        float4 B0 = pA[3], B1 = pA[4], B2 = pA[5];   // corner (s0, zb+1)
        float4 C0 = pB[0], C1 = pB[1], C2 = pB[2];   // corner (s0+1, zb)
        float4 D0 = pB[3], D1 = pB[4], D2 = pB[5];   // corner (s0+1, zb+1)

        // packed 4-corner lerp: c[k] = m0*A + m1*B + m2*C + m3*D (f2 lanes)
        f2 A[6] = {{A0.x,A0.y},{A0.z,A0.w},{A1.x,A1.y},{A1.z,A1.w},{A2.x,A2.y},{A2.z,A2.w}};
        f2 Bv[6] = {{B0.x,B0.y},{B0.z,B0.w},{B1.x,B1.y},{B1.z,B1.w},{B2.x,B2.y},{B2.z,B2.w}};
        f2 Cv[6] = {{C0.x,C0.y},{C0.z,C0.w},{C1.x,C1.y},{C1.z,C1.w},{C2.x,C2.y},{C2.z,C2.w}};
        f2 Dv[6] = {{D0.x,D0.y},{D0.z,D0.w},{D1.x,D1.y},{D1.z,D1.w},{D2.x,D2.y},{D2.z,D2.w}};
        f2 c[6];
        #pragma unroll
        for (int k = 0; k < 6; ++k)
            c[k] = __builtin_elementwise_fma(A[k], m0v,
                   __builtin_elementwise_fma(Bv[k], m1v,
                   __builtin_elementwise_fma(Cv[k], m2v, Dv[k] * m3v)));

        float a0 = acc2r[j][0], a1 = acc2r[j][1], a2 = acc2r[j][2];
        f2 q0 = {a0, a1}, q1 = {a2, 1.0f};
        f2 t0 = __builtin_elementwise_fma(c[0], q0, c[1] * q1);
        f2 t1 = __builtin_elementwise_fma(c[2], q0, c[3] * q1);
        f2 t2 = __builtin_elementwise_fma(c[4], q0, c[5] * q1);

        int oidx = outbase + (y * W_ + x) * 3;
        out[oidx + 0] = t0.x + t0.y;
        out[oidx + 1] = t1.x + t1.y;
        out[oidx + 2] = t2.x + t2.y;
    }
}

extern "C" void kernel_launch(void* const* d_in, const int* in_sizes, int n_in,
                              void* d_out, int out_size, void* d_ws, size_t ws_size,
                              hipStream_t stream) {
    const float* grid   = (const float*)d_in[0];
    const float* guide  = (const float*)d_in[1];
    const float* image  = (const float*)d_in[2];
    const float* conv_w = (const float*)d_in[3];
    const float* conv_b = (const float*)d_in[4];
    float* out = (float*)d_out;

    dim3 block(64, 4, 1);
    dim3 grid_dim(W_ / TW, H_ / TH, B_);  // (16, 128, 4)
    fused_conv_slice<<<grid_dim, block, 0, stream>>>(grid, guide, image, conv_w, conv_b, out);
}

// Round 6
// 135.497 us; speedup vs baseline: 1.3967x; 1.0112x over previous
//
#include <hip/hip_runtime.h>

// Problem constants
#define H_  1024
#define W_  1024
#define B_  4
#define GH  16
#define GW  16
#define GD  8
#define NC  12
#define CELLF (GD * NC)      // 96 floats per (y,x) grid cell
#define YROWF (GW * CELLF)   // 1536 floats per grid y-row

// Tiling: block (64,4) = 256 threads; tile 64 wide x 8 tall; 2 rows/thread.
#define TW 64
#define TH 8
#define LROWS (TH + 2)       // 10 image rows in LDS (+1 halo each side)
#define LCOLS (TW + 2)       // 66 px per LDS row
#define TABH (3 * GD * 16)   // 384 halfs per row-table: 3 cells x 8 z x 16-half slot

typedef _Float16 h2 __attribute__((ext_vector_type(2)));

__device__ __forceinline__ h2 u2h(unsigned int u) { return __builtin_bit_cast(h2, u); }

__global__ __launch_bounds__(256, 8)
void fused_conv_slice(const float* __restrict__ grid,
                      const float* __restrict__ guide,
                      const float* __restrict__ image,
                      const float* __restrict__ conv_w,
                      const float* __restrict__ conv_b,
                      float* __restrict__ out)
{
    __shared__ float4 s_img4[LROWS][LCOLS];                    // 10560 B
    __shared__ __align__(16) unsigned short s_tab[TH][TABH];   //  6144 B (~16.7 KB)

    const int tx  = threadIdx.x;   // 0..63 (one wave per tyq)
    const int tyq = threadIdx.y;   // 0..3
    const int bx  = blockIdx.x;
    const int by  = blockIdx.y;
    const int b   = blockIdx.z;
    const int x0 = bx * TW;
    const int y0 = by * TH;
    const int tid = tyq * 64 + tx;
    const int imgbase = b * (H_ * W_ * 3);

    // ---- stage image tile (+1 halo) ----
    auto stage_px = [&](int rr, int c) {
        int yy = y0 - 1 + rr;
        int xx = x0 - 1 + c;
        float4 v = make_float4(0.f, 0.f, 0.f, 0.f);
        if (yy >= 0 && yy < H_ && xx >= 0 && xx < W_) {
            const float* p = image + imgbase + (yy * W_ + xx) * 3;
            v.x = p[0]; v.y = p[1]; v.z = p[2];
        }
        s_img4[rr][c] = v;
    };
    #pragma unroll
    for (int rr0 = 0; rr0 < LROWS; rr0 += 4) {
        int rr = rr0 + tyq;
        if (rr < LROWS) {
            stage_px(rr, tx);
            if (tx < 2) stage_px(rr, TW + tx);
        }
    }

    // ---- cooperative fill of the 8 row-tables, f16-packed, 32B corner slots ----
    int cells[3];
    cells[0] = max(bx - 1, 0);
    cells[1] = bx;
    cells[2] = min(bx + 1, GW - 1);
    const float* gB = grid + b * (GH * GW * GD * NC);
    {
        int rr = tid >> 5;          // table row 0..7 (32 threads each)
        int le = tid & 31;
        int y  = y0 + rr;
        float gyf = (y + 0.5f) * (1.0f / 64.0f) - 0.5f;
        float fyf = floorf(gyf);
        float tyw = gyf - fyf;
        int iy = (int)fyf;
        int yi0 = min(max(iy, 0), GH - 1);
        int yi1 = min(max(iy + 1, 0), GH - 1);
        float wy0 = 1.0f - tyw, wy1 = tyw;
        const float4* G0 = (const float4*)(gB + yi0 * YROWF);
        const float4* G1 = (const float4*)(gB + yi1 * YROWF);
        #pragma unroll
        for (int k = 0; k < 3; ++k) {
            int e = le + k * 32;                 // 72 float4 per row-table
            if (e < 72) {
                int s  = (e >= 48) ? 2 : ((e >= 24) ? 1 : 0);   // cell slot
                int re = e - s * 24;             // 0..23 within cell
                int z  = re / 3;                 // 0..7
                int c4 = re - z * 3;             // float4 index within corner
                int off = cells[s] * 24 + re;
                float4 v0 = G0[off], v1 = G1[off];
                h2 p0, p1;
                p0.x = (_Float16)(wy0 * v0.x + wy1 * v1.x);
                p0.y = (_Float16)(wy0 * v0.y + wy1 * v1.y);
                p1.x = (_Float16)(wy0 * v0.z + wy1 * v1.z);
                p1.y = (_Float16)(wy0 * v0.w + wy1 * v1.w);
                uint2 u;
                u.x = __builtin_bit_cast(unsigned int, p0);
                u.y = __builtin_bit_cast(unsigned int, p1);
                // corner (s,z) occupies halfs [(s*8+z)*16, +12), padded to 16
                *(uint2*)&s_tab[rr][(s * GD + z) * 16 + c4 * 4] = u;
            }
        }
    }

    // ---- guide prefetch ----
    const int x = x0 + tx;
    const int lr = tyq * 2;
    const int guidebase = b * (H_ * W_);
    float g2[2];
    #pragma unroll
    for (int j = 0; j < 2; ++j)
        g2[j] = guide[guidebase + (y0 + lr + j) * W_ + x];

    // ---- conv weights: uniform reads -> SGPRs ----
    float wgt[81];
    #pragma unroll
    for (int i = 0; i < 81; ++i) wgt[i] = conv_w[i];
    float bias0 = conv_b[0], bias1 = conv_b[1], bias2 = conv_b[2];

    __syncthreads();  // the ONLY barrier

    // ---- conv for this thread's 2 rows (f32, SGPR weights — proven path) ----
    float4 r0[3], r1[3], r2[3];
    float acc2r[2][3];

    auto loadrow = [&](int r, float4* d) {
        d[0] = s_img4[r][tx];
        d[1] = s_img4[r][tx + 1];
        d[2] = s_img4[r][tx + 2];
    };
    auto conv3 = [&](const float4* ra, const float4* rb, const float4* rc, float* acc) {
        acc[0] = bias0; acc[1] = bias1; acc[2] = bias2;
        const float4* rows[3] = {ra, rb, rc};
        #pragma unroll
        for (int kh = 0; kh < 3; ++kh)
            #pragma unroll
            for (int kw = 0; kw < 3; ++kw) {
                float4 v4 = rows[kh][kw];
                float v[3] = {v4.x, v4.y, v4.z};
                #pragma unroll
                for (int ci = 0; ci < 3; ++ci) {
                    int wb = ((kh * 3 + kw) * 3 + ci) * 3;
                    acc[0] += v[ci] * wgt[wb + 0];
                    acc[1] += v[ci] * wgt[wb + 1];
                    acc[2] += v[ci] * wgt[wb + 2];
                }
            }
    };

    loadrow(lr + 0, r0); loadrow(lr + 1, r1); loadrow(lr + 2, r2);
    conv3(r0, r1, r2, acc2r[0]);
    loadrow(lr + 3, r0);
    conv3(r1, r2, r0, acc2r[1]);

    // ---- per-thread x-interp setup ----
    float gxf = (x + 0.5f) * (1.0f / 64.0f) - 0.5f;
    float fxf = floorf(gxf);
    float txw = gxf - fxf;
    float wxa = 1.0f - txw, wxb = txw;
    int s0 = (int)fxf - (bx - 1);   // table x-slot of left corner: 0 or 1

    const int outbase = b * (H_ * W_ * 3);

    #pragma unroll
    for (int j = 0; j < 2; ++j) {
        int y = y0 + lr + j;
        const unsigned short* Tr = &s_tab[lr + j][0];

        float gzf = g2[j] * 8.0f - 0.5f;
        float fzf = floorf(gzf);
        float tz = gzf - fzf;
        int iz = (int)fzf;                    // -1..7
        int zb = min(max(iz, 0), GD - 2);     // contiguous z-pair base
        float wA = (iz < 0) ? 1.0f : ((iz > GD - 2) ? 0.0f : (1.0f - tz));
        float wB = 1.0f - wA;

        float m0 = wxa * wA, m1 = wxa * wB, m2 = wxb * wA, m3 = wxb * wB;
        h2 m0h = {(_Float16)m0, (_Float16)m0};
        h2 m1h = {(_Float16)m1, (_Float16)m1};
        h2 m2h = {(_Float16)m2, (_Float16)m2};
        h2 m3h = {(_Float16)m3, (_Float16)m3};

        // corner slots: A=(s0,zb) B=(s0,zb+1) C=(s0+1,zb) D=(s0+1,zb+1)
        const unsigned short* pA = Tr + (s0 * GD + zb) * 16;
        uint4 Alo = *(const uint4*)(pA);            uint2 Ahi = *(const uint2*)(pA + 8);
        uint4 Blo = *(const uint4*)(pA + 16);       uint2 Bhi = *(const uint2*)(pA + 24);
        uint4 Clo = *(const uint4*)(pA + GD * 16);      uint2 Chi = *(const uint2*)(pA + GD * 16 + 8);
        uint4 Dlo = *(const uint4*)(pA + GD * 16 + 16); uint2 Dhi = *(const uint2*)(pA + GD * 16 + 24);

        h2 A[6] = {u2h(Alo.x), u2h(Alo.y), u2h(Alo.z), u2h(Alo.w), u2h(Ahi.x), u2h(Ahi.y)};
        h2 Bv[6] = {u2h(Blo.x), u2h(Blo.y), u2h(Blo.z), u2h(Blo.w), u2h(Bhi.x), u2h(Bhi.y)};
        h2 Cv[6] = {u2h(Clo.x), u2h(Clo.y), u2h(Clo.z), u2h(Clo.w), u2h(Chi.x), u2h(Chi.y)};
        h2 Dv[6] = {u2h(Dlo.x), u2h(Dlo.y), u2h(Dlo.z), u2h(Dlo.w), u2h(Dhi.x), u2h(Dhi.y)};

        // packed-f16 4-corner lerp
        h2 c[6];
        #pragma unroll
        for (int k = 0; k < 6; ++k)
            c[k] = __builtin_elementwise_fma(A[k], m0h,
                   __builtin_elementwise_fma(Bv[k], m1h,
                   __builtin_elementwise_fma(Cv[k], m2h, Dv[k] * m3h)));

        // apply: out_o = c[2o]·{a0,a1} + c[2o+1]·{a2,1}  (fdot2, f32 accumulate)
        float a0 = acc2r[j][0], a1 = acc2r[j][1], a2 = acc2r[j][2];
        h2 q01 = {(_Float16)a0, (_Float16)a1};
        h2 q21 = {(_Float16)a2, (_Float16)1.0f};

        int oidx = outbase + (y * W_ + x) * 3;
        #pragma unroll
        for (int o3 = 0; o3 < 3; ++o3) {
            float t = __builtin_amdgcn_fdot2(c[2 * o3 + 1], q21, 0.0f, false);
            out[oidx + o3] = __builtin_amdgcn_fdot2(c[2 * o3], q01, t, false);
        }
    }
}

extern "C" void kernel_launch(void* const* d_in, const int* in_sizes, int n_in,
                              void* d_out, int out_size, void* d_ws, size_t ws_size,
                              hipStream_t stream) {
    const float* grid   = (const float*)d_in[0];
    const float* guide  = (const float*)d_in[1];
    const float* image  = (const float*)d_in[2];
    const float* conv_w = (const float*)d_in[3];
    const float* conv_b = (const float*)d_in[4];
    float* out = (float*)d_out;

    dim3 block(64, 4, 1);
    dim3 grid_dim(W_ / TW, H_ / TH, B_);  // (16, 128, 4)
    fused_conv_slice<<<grid_dim, block, 0, stream>>>(grid, guide, image, conv_w, conv_b, out);
}

// Round 7
// 134.731 us; speedup vs baseline: 1.4046x; 1.0057x over previous
//
#include <hip/hip_runtime.h>

// Problem constants
#define H_  1024
#define W_  1024
#define B_  4
#define GH  16
#define GW  16
#define GD  8
#define NC  12
#define CELLF (GD * NC)      // 96 floats per (y,x) grid cell
#define YROWF (GW * CELLF)   // 1536 floats per grid y-row

// Tiling: block (64,4) = 256 threads; tile 64 wide x 8 tall; 2 rows/thread.
#define TW 64
#define TH 8
#define LROWS (TH + 2)       // 10 image rows in LDS (+1 halo each side)
#define LCOLS (TW + 2)       // 66 px per LDS row

typedef _Float16 h2 __attribute__((ext_vector_type(2)));

__device__ __forceinline__ h2 u2h(unsigned int u) { return __builtin_bit_cast(h2, u); }

__global__ __launch_bounds__(256, 8)
void fused_conv_slice(const float* __restrict__ grid,
                      const float* __restrict__ guide,
                      const float* __restrict__ image,
                      const float* __restrict__ conv_w,
                      const float* __restrict__ conv_b,
                      float* __restrict__ out)
{
    __shared__ float4 s_img4[LROWS][LCOLS];        // 10560 B
    // f16 y-lerped tables, split for bank spread:
    //   T128: coeffs 0..7 of corner (cell s, z) -> 16B stride (8 bank-groups)
    //   T64 : coeffs 8..11                      ->  8B stride (16 start banks)
    __shared__ uint4 s_t128[TH][3 * GD];           // 3072 B
    __shared__ uint2 s_t64[TH][3 * GD];            // 1536 B   (~14.8 KB total)

    const int tx  = threadIdx.x;   // 0..63 (one wave per tyq)
    const int tyq = threadIdx.y;   // 0..3
    const int bx  = blockIdx.x;
    const int by  = blockIdx.y;
    const int b   = blockIdx.z;
    const int x0 = bx * TW;
    const int y0 = by * TH;
    const int tid = tyq * 64 + tx;
    const int imgbase = b * (H_ * W_ * 3);

    // ---- stage image tile (+1 halo) ----
    auto stage_px = [&](int rr, int c) {
        int yy = y0 - 1 + rr;
        int xx = x0 - 1 + c;
        float4 v = make_float4(0.f, 0.f, 0.f, 0.f);
        if (yy >= 0 && yy < H_ && xx >= 0 && xx < W_) {
            const float* p = image + imgbase + (yy * W_ + xx) * 3;
            v.x = p[0]; v.y = p[1]; v.z = p[2];
        }
        s_img4[rr][c] = v;
    };
    #pragma unroll
    for (int rr0 = 0; rr0 < LROWS; rr0 += 4) {
        int rr = rr0 + tyq;
        if (rr < LROWS) {
            stage_px(rr, tx);
            if (tx < 2) stage_px(rr, TW + tx);
        }
    }

    // ---- cooperative fill of the 8 row-tables (f16, split layout) ----
    int cells[3];
    cells[0] = max(bx - 1, 0);
    cells[1] = bx;
    cells[2] = min(bx + 1, GW - 1);
    const float* gB = grid + b * (GH * GW * GD * NC);
    {
        int rr = tid >> 5;          // table row 0..7 (32 threads each)
        int le = tid & 31;
        int y  = y0 + rr;
        float gyf = (y + 0.5f) * (1.0f / 64.0f) - 0.5f;
        float fyf = floorf(gyf);
        float tyw = gyf - fyf;
        int iy = (int)fyf;
        int yi0 = min(max(iy, 0), GH - 1);
        int yi1 = min(max(iy + 1, 0), GH - 1);
        float wy0 = 1.0f - tyw, wy1 = tyw;
        const float4* G0 = (const float4*)(gB + yi0 * YROWF);
        const float4* G1 = (const float4*)(gB + yi1 * YROWF);
        #pragma unroll
        for (int k = 0; k < 3; ++k) {
            int e = le + k * 32;                 // 72 float4 per row-table
            if (e < 72) {
                int s  = (e >= 48) ? 2 : ((e >= 24) ? 1 : 0);   // cell slot
                int re = e - s * 24;             // 0..23 within cell
                int z  = re / 3;                 // 0..7
                int c4 = re - z * 3;             // float4 index within corner (0..2)
                int off = cells[s] * 24 + re;
                float4 v0 = G0[off], v1 = G1[off];
                h2 p0, p1;
                p0.x = (_Float16)(wy0 * v0.x + wy1 * v1.x);
                p0.y = (_Float16)(wy0 * v0.y + wy1 * v1.y);
                p1.x = (_Float16)(wy0 * v0.z + wy1 * v1.z);
                p1.y = (_Float16)(wy0 * v0.w + wy1 * v1.w);
                uint2 u;
                u.x = __builtin_bit_cast(unsigned int, p0);
                u.y = __builtin_bit_cast(unsigned int, p1);
                int ci = s * GD + z;
                unsigned short* dst = (c4 == 2)
                    ? (unsigned short*)&s_t64[rr][ci]
                    : (unsigned short*)&s_t128[rr][ci] + c4 * 4;
                *(uint2*)dst = u;
            }
        }
    }

    // ---- guide prefetch ----
    const int x = x0 + tx;
    const int lr = tyq * 2;
    const int guidebase = b * (H_ * W_);
    float g2[2];
    #pragma unroll
    for (int j = 0; j < 2; ++j)
        g2[j] = guide[guidebase + (y0 + lr + j) * W_ + x];

    // ---- conv weights: uniform reads -> SGPRs ----
    float wgt[81];
    #pragma unroll
    for (int i = 0; i < 81; ++i) wgt[i] = conv_w[i];
    float bias0 = conv_b[0], bias1 = conv_b[1], bias2 = conv_b[2];

    __syncthreads();  // the ONLY barrier

    // ---- conv for this thread's 2 rows (f32, SGPR weights) ----
    float4 r0[3], r1[3], r2[3];
    float acc2r[2][3];

    auto loadrow = [&](int r, float4* d) {
        d[0] = s_img4[r][tx];
        d[1] = s_img4[r][tx + 1];
        d[2] = s_img4[r][tx + 2];
    };
    auto conv3 = [&](const float4* ra, const float4* rb, const float4* rc, float* acc) {
        acc[0] = bias0; acc[1] = bias1; acc[2] = bias2;
        const float4* rows[3] = {ra, rb, rc};
        #pragma unroll
        for (int kh = 0; kh < 3; ++kh)
            #pragma unroll
            for (int kw = 0; kw < 3; ++kw) {
                float4 v4 = rows[kh][kw];
                float v[3] = {v4.x, v4.y, v4.z};
                #pragma unroll
                for (int ci = 0; ci < 3; ++ci) {
                    int wb = ((kh * 3 + kw) * 3 + ci) * 3;
                    acc[0] += v[ci] * wgt[wb + 0];
                    acc[1] += v[ci] * wgt[wb + 1];
                    acc[2] += v[ci] * wgt[wb + 2];
                }
            }
    };

    loadrow(lr + 0, r0); loadrow(lr + 1, r1); loadrow(lr + 2, r2);
    conv3(r0, r1, r2, acc2r[0]);
    loadrow(lr + 3, r0);
    conv3(r1, r2, r0, acc2r[1]);

    // ---- per-thread x-interp setup ----
    float gxf = (x + 0.5f) * (1.0f / 64.0f) - 0.5f;
    float fxf = floorf(gxf);
    float txw = gxf - fxf;
    float wxa = 1.0f - txw, wxb = txw;
    int s0 = (int)fxf - (bx - 1);   // table x-slot of left corner: 0 or 1

    const int outbase = b * (H_ * W_ * 3);

    #pragma unroll
    for (int j = 0; j < 2; ++j) {
        int y = y0 + lr + j;
        const uint4* T128 = &s_t128[lr + j][0];
        const uint2* T64  = &s_t64[lr + j][0];

        float gzf = g2[j] * 8.0f - 0.5f;
        float fzf = floorf(gzf);
        float tz = gzf - fzf;
        int iz = (int)fzf;                    // -1..7
        int zb = min(max(iz, 0), GD - 2);     // contiguous z-pair base
        float wA = (iz < 0) ? 1.0f : ((iz > GD - 2) ? 0.0f : (1.0f - tz));
        float wB = 1.0f - wA;

        float m0 = wxa * wA, m1 = wxa * wB, m2 = wxb * wA, m3 = wxb * wB;
        h2 m0h = {(_Float16)m0, (_Float16)m0};
        h2 m1h = {(_Float16)m1, (_Float16)m1};
        h2 m2h = {(_Float16)m2, (_Float16)m2};
        h2 m3h = {(_Float16)m3, (_Float16)m3};

        // corners: A=(s0,zb) B=(s0,zb+1) C=(s0+1,zb) D=(s0+1,zb+1)
        int ci0 = s0 * GD + zb;
        uint4 Alo = T128[ci0];          uint2 Ahi = T64[ci0];
        uint4 Blo = T128[ci0 + 1];      uint2 Bhi = T64[ci0 + 1];
        uint4 Clo = T128[ci0 + GD];     uint2 Chi = T64[ci0 + GD];
        uint4 Dlo = T128[ci0 + GD + 1]; uint2 Dhi = T64[ci0 + GD + 1];

        h2 A[6]  = {u2h(Alo.x), u2h(Alo.y), u2h(Alo.z), u2h(Alo.w), u2h(Ahi.x), u2h(Ahi.y)};
        h2 Bv[6] = {u2h(Blo.x), u2h(Blo.y), u2h(Blo.z), u2h(Blo.w), u2h(Bhi.x), u2h(Bhi.y)};
        h2 Cv[6] = {u2h(Clo.x), u2h(Clo.y), u2h(Clo.z), u2h(Clo.w), u2h(Chi.x), u2h(Chi.y)};
        h2 Dv[6] = {u2h(Dlo.x), u2h(Dlo.y), u2h(Dlo.z), u2h(Dlo.w), u2h(Dhi.x), u2h(Dhi.y)};

        // packed-f16 4-corner lerp
        h2 c[6];
        #pragma unroll
        for (int k = 0; k < 6; ++k)
            c[k] = __builtin_elementwise_fma(A[k], m0h,
                   __builtin_elementwise_fma(Bv[k], m1h,
                   __builtin_elementwise_fma(Cv[k], m2h, Dv[k] * m3h)));

        // apply: out_o = c[2o]·{a0,a1} + c[2o+1]·{a2,1}  (fdot2, f32 accumulate)
        float a0 = acc2r[j][0], a1 = acc2r[j][1], a2 = acc2r[j][2];
        h2 q01 = {(_Float16)a0, (_Float16)a1};
        h2 q21 = {(_Float16)a2, (_Float16)1.0f};

        int oidx = outbase + (y * W_ + x) * 3;
        #pragma unroll
        for (int o3 = 0; o3 < 3; ++o3) {
            float t = __builtin_amdgcn_fdot2(c[2 * o3 + 1], q21, 0.0f, false);
            out[oidx + o3] = __builtin_amdgcn_fdot2(c[2 * o3], q01, t, false);
        }
    }
}

extern "C" void kernel_launch(void* const* d_in, const int* in_sizes, int n_in,
                              void* d_out, int out_size, void* d_ws, size_t ws_size,
                              hipStream_t stream) {
    const float* grid   = (const float*)d_in[0];
    const float* guide  = (const float*)d_in[1];
    const float* image  = (const float*)d_in[2];
    const float* conv_w = (const float*)d_in[3];
    const float* conv_b = (const float*)d_in[4];
    float* out = (float*)d_out;

    dim3 block(64, 4, 1);
    dim3 grid_dim(W_ / TW, H_ / TH, B_);  // (16, 128, 4)
    fused_conv_slice<<<grid_dim, block, 0, stream>>>(grid, guide, image, conv_w, conv_b, out);
}